// Round 4
// baseline (100.475 us; speedup 1.0000x reference)
//
#include <hip/hip_runtime.h>
#include <math.h>

// Problem constants (from reference): B,C,N,D,S = 512,256,2048,64,3
constexpr int Bb = 512;
constexpr int Cc = 256;
constexpr int Nn = 2048;
constexpr int Dd = 64;
constexpr int EMIT = Dd + 1 + 1 + 3 + 1;  // 70
constexpr int BLOCK = 512;
constexpr int NW = BLOCK / 64;            // waves per block = 8

__global__ __launch_bounds__(BLOCK, 4)
void ntm_read_head_kernel(const float* __restrict__ co,
                          const float* __restrict__ wprev,
                          const float* __restrict__ M,
                          const float* __restrict__ W,
                          const float* __restrict__ bias,
                          float* __restrict__ out_r,
                          float* __restrict__ out_w)
{
    const int b    = blockIdx.x;
    const int t    = threadIdx.x;
    const int lane = t & 63;
    const int wv   = t >> 6;

    __shared__ __align__(16) float fc[EMIT + 2];   // tanh(co@W+b), padded
    __shared__ float sc[8];                        // beta,g,s0,s1,s2,gamma,1/kmag
    __shared__ float zbuf[Nn];                     // beta*cos -> exp()
    __shared__ float wgbuf[Nn];                    // gated weights
    __shared__ float wtbuf[Nn];                    // raised/normalized weights
    __shared__ float red[NW];                      // block-reduce scratch
    __shared__ float rred[NW][Dd];                 // r_t partial per wave

    // ---------- fc = tanh(co[b] @ W + bias) : 70 dots of length 256 ----------
    const float* corow = co + (size_t)b * Cc;
    if (t < EMIT * 4) {
        const int j = t >> 2, p = t & 3;
        float s = 0.f;
        const float* wp = W + j;
        #pragma unroll 8
        for (int c = p * 64; c < p * 64 + 64; ++c)
            s += corow[c] * wp[(size_t)c * EMIT];
        s += __shfl_xor(s, 1);
        s += __shfl_xor(s, 2);
        if (p == 0) fc[j] = tanhf(s + bias[j]);
    }
    __syncthreads();

    // ---------- head scalars ----------
    if (t < 64) {
        float kk  = fc[t];
        float ksq = kk * kk;
        #pragma unroll
        for (int o = 1; o < 64; o <<= 1) ksq += __shfl_xor(ksq, o);
        if (t == 0) {
            float kmag  = sqrtf(ksq);
            float beta  = log1pf(expf(fc[Dd]));          // softplus
            float g     = 1.f / (1.f + expf(-fc[Dd + 1]));
            float f0 = fc[Dd + 2], f1 = fc[Dd + 3], f2 = fc[Dd + 4];
            float mx = fmaxf(f0, fmaxf(f1, f2));
            float e0 = expf(f0 - mx), e1 = expf(f1 - mx), e2 = expf(f2 - mx);
            float ei = 1.f / (e0 + e1 + e2);
            float gamma = 1.f + log1pf(expf(fc[Dd + 5]));
            sc[0] = beta; sc[1] = g;
            sc[2] = e0 * ei; sc[3] = e1 * ei; sc[4] = e2 * ei;
            sc[5] = gamma; sc[6] = 1.f / kmag;
        }
    }
    __syncthreads();

    // ---------- pass 1: z[n] = beta * cos(k, M[b,n,:]) ----------
    const size_t mbase = (size_t)b * Nn * Dd;
    const int grp = t >> 4;          // 32 row-groups
    const int dk  = t & 15;          // 16 lanes per row, float4 each
    {
        const float beta = sc[0];
        const float kinv = sc[6];
        const float4 kf = *(const float4*)&fc[dk * 4];
        for (int n = grp; n < Nn; n += BLOCK / 16) {
            const float4 m = *(const float4*)&M[mbase + (size_t)n * Dd + dk * 4];
            float dot = kf.x * m.x + kf.y * m.y + kf.z * m.z + kf.w * m.w;
            float msq = m.x * m.x + m.y * m.y + m.z * m.z + m.w * m.w;
            #pragma unroll
            for (int o = 1; o < 16; o <<= 1) {
                dot += __shfl_xor(dot, o);
                msq += __shfl_xor(msq, o);
            }
            if (dk == 0) zbuf[n] = beta * dot * kinv / sqrtf(msq);
        }
    }
    __syncthreads();

    // ---------- softmax over n (block-wide) ----------
    float lm = -3.4e38f;
    for (int n = t; n < Nn; n += BLOCK) lm = fmaxf(lm, zbuf[n]);
    #pragma unroll
    for (int o = 1; o < 64; o <<= 1) lm = fmaxf(lm, __shfl_xor(lm, o));
    if (lane == 0) red[wv] = lm;
    __syncthreads();
    float zmax = red[0];
    #pragma unroll
    for (int w = 1; w < NW; ++w) zmax = fmaxf(zmax, red[w]);
    __syncthreads();                                  // protect red before reuse

    float ls = 0.f;
    for (int n = t; n < Nn; n += BLOCK) {
        float e = expf(zbuf[n] - zmax);
        zbuf[n] = e;
        ls += e;
    }
    #pragma unroll
    for (int o = 1; o < 64; o <<= 1) ls += __shfl_xor(ls, o);
    if (lane == 0) red[wv] = ls;
    __syncthreads();
    float Zs = 0.f;
    #pragma unroll
    for (int w = 0; w < NW; ++w) Zs += red[w];

    // ---------- gate with w_prev ----------
    {
        const float g = sc[1];
        const float invZ = 1.f / Zs;
        const float* wpv = wprev + (size_t)b * Nn;
        for (int n = t; n < Nn; n += BLOCK)
            wgbuf[n] = g * zbuf[n] * invZ + (1.f - g) * wpv[n];
    }
    __syncthreads();   // wgbuf ready (also protects red before next write)

    // ---------- circular conv (S=3) + pow + sum ----------
    float lsum = 0.f;
    {
        const float s0 = sc[2], s1 = sc[3], s2 = sc[4], gamma = sc[5];
        for (int n = t; n < Nn; n += BLOCK) {
            // w_tilde[n] = s0*wg[(n+1)%N] + s1*wg[n] + s2*wg[(n-1)%N]
            float wt_ = s0 * wgbuf[(n + 1) & (Nn - 1)]
                      + s1 * wgbuf[n]
                      + s2 * wgbuf[(n - 1) & (Nn - 1)];
            float wr = powf(wt_, gamma);
            wtbuf[n] = wr;
            lsum += wr;
        }
    }
    #pragma unroll
    for (int o = 1; o < 64; o <<= 1) lsum += __shfl_xor(lsum, o);
    if (lane == 0) red[wv] = lsum;
    __syncthreads();
    float Ws = 0.f;
    #pragma unroll
    for (int w = 0; w < NW; ++w) Ws += red[w];

    // ---------- normalize + store w_t ----------
    {
        const float inv = 1.f / Ws;
        float* ow = out_w + (size_t)b * Nn;
        for (int n = t; n < Nn; n += BLOCK) {
            float v = wtbuf[n] * inv;
            wtbuf[n] = v;
            ow[n] = v;
        }
    }
    __syncthreads();   // wtbuf final for pass 2

    // ---------- pass 2: r_t[d] = sum_n w_t[n] * M[b,n,d] ----------
    {
        float4 acc = make_float4(0.f, 0.f, 0.f, 0.f);
        for (int n = grp; n < Nn; n += BLOCK / 16) {
            const float w = wtbuf[n];
            const float4 m = *(const float4*)&M[mbase + (size_t)n * Dd + dk * 4];
            acc.x += w * m.x; acc.y += w * m.y;
            acc.z += w * m.z; acc.w += w * m.w;
        }
        #pragma unroll
        for (int o = 16; o < 64; o <<= 1) {
            acc.x += __shfl_xor(acc.x, o);
            acc.y += __shfl_xor(acc.y, o);
            acc.z += __shfl_xor(acc.z, o);
            acc.w += __shfl_xor(acc.w, o);
        }
        if (lane < 16) {
            rred[wv][lane * 4 + 0] = acc.x;
            rred[wv][lane * 4 + 1] = acc.y;
            rred[wv][lane * 4 + 2] = acc.z;
            rred[wv][lane * 4 + 3] = acc.w;
        }
    }
    __syncthreads();
    if (t < Dd) {
        float r = 0.f;
        #pragma unroll
        for (int w = 0; w < NW; ++w) r += rred[w][t];
        out_r[(size_t)b * Dd + t] = r;
    }
}

extern "C" void kernel_launch(void* const* d_in, const int* in_sizes, int n_in,
                              void* d_out, int out_size, void* d_ws, size_t ws_size,
                              hipStream_t stream) {
    const float* co    = (const float*)d_in[0];   // (B, C)
    const float* wprev = (const float*)d_in[1];   // (B, N)
    const float* M     = (const float*)d_in[2];   // (B, N, D)
    const float* W     = (const float*)d_in[3];   // (C, 70)
    const float* bias  = (const float*)d_in[4];   // (70,)
    float* out = (float*)d_out;                   // r_t (B*D) then w_t (B*N)
    float* out_r = out;
    float* out_w = out + (size_t)Bb * Dd;

    ntm_read_head_kernel<<<Bb, BLOCK, 0, stream>>>(co, wprev, M, W, bias, out_r, out_w);
}

// Round 5
// 88.375 us; speedup vs baseline: 1.1369x; 1.1369x over previous
//
#include <hip/hip_runtime.h>
#include <math.h>

// Problem constants (from reference): B,C,N,D,S = 512,256,2048,64,3
constexpr int Bb = 512;
constexpr int Cc = 256;
constexpr int Nn = 2048;
constexpr int Dd = 64;
constexpr int EMIT = Dd + 1 + 1 + 3 + 1;  // 70
constexpr int BLOCK = 1024;
constexpr int NW = BLOCK / 64;            // waves per block = 16

__global__ __launch_bounds__(BLOCK, 8)
void ntm_read_head_kernel(const float* __restrict__ co,
                          const float* __restrict__ wprev,
                          const float* __restrict__ M,
                          const float* __restrict__ W,
                          const float* __restrict__ bias,
                          float* __restrict__ out_r,
                          float* __restrict__ out_w)
{
    const int b    = blockIdx.x;
    const int t    = threadIdx.x;
    const int lane = t & 63;
    const int wv   = t >> 6;

    __shared__ __align__(16) float fc[EMIT + 2];   // tanh(co@W+b)
    __shared__ float sc[8];                        // beta,g,s0,s1,s2,gamma,1/kmag
    __shared__ __align__(16) float zbuf[Nn];       // fc partials -> beta*cos -> exp
    __shared__ float wgbuf[Nn];                    // gated weights
    __shared__ float wtbuf[Nn];                    // raised/normalized weights
    __shared__ float red[NW];                      // block-reduce scratch
    __shared__ float rred[NW][Dd];                 // r_t partial per wave

    // ---------- fc = tanh(co[b] @ W + bias) ----------
    // 980 threads: j = t%70 (output), part = t/70 (c-slice of 19).
    // W reads are coalesced along j (70 consecutive floats per c).
    const float* corow = co + (size_t)b * Cc;
    {
        float* fcp = zbuf;                 // reuse zbuf as 14x70 partial buffer
        if (t < 980) {
            const int j    = t % EMIT;
            const int part = t / EMIT;     // 0..13
            const int c0 = part * 19;
            const int c1 = (c0 + 19 < Cc) ? c0 + 19 : Cc;
            float s = 0.f;
            for (int c = c0; c < c1; ++c)
                s = fmaf(corow[c], W[(size_t)c * EMIT + j], s);
            fcp[part * EMIT + j] = s;
        }
        __syncthreads();
        if (t < EMIT) {
            float s = bias[t];
            #pragma unroll
            for (int w = 0; w < 14; ++w) s += fcp[w * EMIT + t];
            fc[t] = tanhf(s);
        }
    }
    __syncthreads();

    // ---------- head scalars (wave 0) ----------
    if (t < 64) {
        float kk  = fc[t];
        float ksq = kk * kk;
        #pragma unroll
        for (int o = 1; o < 64; o <<= 1) ksq += __shfl_xor(ksq, o);
        if (t == 0) {
            float kmag  = sqrtf(ksq);
            float beta  = log1pf(expf(fc[Dd]));          // softplus
            float g     = 1.f / (1.f + expf(-fc[Dd + 1]));
            float f0 = fc[Dd + 2], f1 = fc[Dd + 3], f2 = fc[Dd + 4];
            float mx = fmaxf(f0, fmaxf(f1, f2));
            float e0 = expf(f0 - mx), e1 = expf(f1 - mx), e2 = expf(f2 - mx);
            float ei = 1.f / (e0 + e1 + e2);
            float gamma = 1.f + log1pf(expf(fc[Dd + 5]));
            sc[0] = beta; sc[1] = g;
            sc[2] = e0 * ei; sc[3] = e1 * ei; sc[4] = e2 * ei;
            sc[5] = gamma; sc[6] = 1.f / kmag;
        }
    }
    __syncthreads();

    // ---------- pass 1: z[n] = beta * cos(k, M[b,n,:]) ----------
    // 4 lanes per row, 4 independent float4 loads per lane (16 d each),
    // then only 2 shfl stages x 2 values.
    const size_t mbase = (size_t)b * Nn * Dd;
    {
        const int rg = t >> 2;           // 0..255 row within slab
        const int p  = t & 3;            // lane within row
        const float beta = sc[0];
        const float kinv = sc[6];
        const float4 k0 = *(const float4*)&fc[p * 16 + 0];
        const float4 k1 = *(const float4*)&fc[p * 16 + 4];
        const float4 k2 = *(const float4*)&fc[p * 16 + 8];
        const float4 k3 = *(const float4*)&fc[p * 16 + 12];
        for (int n0 = 0; n0 < Nn; n0 += BLOCK / 4) {
            const int n = n0 + rg;
            const float4* mr = (const float4*)&M[mbase + (size_t)n * Dd + p * 16];
            const float4 m0 = mr[0];
            const float4 m1 = mr[1];
            const float4 m2 = mr[2];
            const float4 m3 = mr[3];
            float dot = m0.x*k0.x + m0.y*k0.y + m0.z*k0.z + m0.w*k0.w
                      + m1.x*k1.x + m1.y*k1.y + m1.z*k1.z + m1.w*k1.w
                      + m2.x*k2.x + m2.y*k2.y + m2.z*k2.z + m2.w*k2.w
                      + m3.x*k3.x + m3.y*k3.y + m3.z*k3.z + m3.w*k3.w;
            float msq = m0.x*m0.x + m0.y*m0.y + m0.z*m0.z + m0.w*m0.w
                      + m1.x*m1.x + m1.y*m1.y + m1.z*m1.z + m1.w*m1.w
                      + m2.x*m2.x + m2.y*m2.y + m2.z*m2.z + m2.w*m2.w
                      + m3.x*m3.x + m3.y*m3.y + m3.z*m3.z + m3.w*m3.w;
            dot += __shfl_xor(dot, 1);
            msq += __shfl_xor(msq, 1);
            dot += __shfl_xor(dot, 2);
            msq += __shfl_xor(msq, 2);
            if (p == 0) zbuf[n] = beta * dot * kinv / sqrtf(msq);
        }
    }
    __syncthreads();

    // ---------- softmax over n (block-wide) ----------
    float lm = -3.4e38f;
    for (int n = t; n < Nn; n += BLOCK) lm = fmaxf(lm, zbuf[n]);
    #pragma unroll
    for (int o = 1; o < 64; o <<= 1) lm = fmaxf(lm, __shfl_xor(lm, o));
    if (lane == 0) red[wv] = lm;
    __syncthreads();
    float zmax = red[0];
    #pragma unroll
    for (int w = 1; w < NW; ++w) zmax = fmaxf(zmax, red[w]);
    __syncthreads();                                  // protect red before reuse

    float ls = 0.f;
    for (int n = t; n < Nn; n += BLOCK) {
        float e = expf(zbuf[n] - zmax);
        zbuf[n] = e;
        ls += e;
    }
    #pragma unroll
    for (int o = 1; o < 64; o <<= 1) ls += __shfl_xor(ls, o);
    if (lane == 0) red[wv] = ls;
    __syncthreads();
    float Zs = 0.f;
    #pragma unroll
    for (int w = 0; w < NW; ++w) Zs += red[w];

    // ---------- gate with w_prev ----------
    {
        const float g = sc[1];
        const float invZ = 1.f / Zs;
        const float* wpv = wprev + (size_t)b * Nn;
        for (int n = t; n < Nn; n += BLOCK)
            wgbuf[n] = g * zbuf[n] * invZ + (1.f - g) * wpv[n];
    }
    __syncthreads();   // wgbuf ready (also protects red before next write)

    // ---------- circular conv (S=3) + pow + sum ----------
    float lsum = 0.f;
    {
        const float s0 = sc[2], s1 = sc[3], s2 = sc[4], gamma = sc[5];
        for (int n = t; n < Nn; n += BLOCK) {
            float wt_ = s0 * wgbuf[(n + 1) & (Nn - 1)]
                      + s1 * wgbuf[n]
                      + s2 * wgbuf[(n - 1) & (Nn - 1)];
            float wr = powf(wt_, gamma);
            wtbuf[n] = wr;
            lsum += wr;
        }
    }
    #pragma unroll
    for (int o = 1; o < 64; o <<= 1) lsum += __shfl_xor(lsum, o);
    if (lane == 0) red[wv] = lsum;
    __syncthreads();
    float Ws = 0.f;
    #pragma unroll
    for (int w = 0; w < NW; ++w) Ws += red[w];

    // ---------- normalize + store w_t ----------
    {
        const float inv = 1.f / Ws;
        float* ow = out_w + (size_t)b * Nn;
        for (int n = t; n < Nn; n += BLOCK) {
            float v = wtbuf[n] * inv;
            wtbuf[n] = v;
            ow[n] = v;
        }
    }
    __syncthreads();   // wtbuf final for pass 2

    // ---------- pass 2: r_t[d] = sum_n w_t[n] * M[b,n,d] ----------
    {
        const int grp = t >> 4;      // 64 row-groups
        const int dk  = t & 15;      // 16 lanes per row, float4 each
        float4 acc = make_float4(0.f, 0.f, 0.f, 0.f);
        #pragma unroll 2
        for (int n = grp; n < Nn; n += BLOCK / 16) {
            const float w = wtbuf[n];
            const float4 m = *(const float4*)&M[mbase + (size_t)n * Dd + dk * 4];
            acc.x += w * m.x; acc.y += w * m.y;
            acc.z += w * m.z; acc.w += w * m.w;
        }
        #pragma unroll
        for (int o = 16; o < 64; o <<= 1) {
            acc.x += __shfl_xor(acc.x, o);
            acc.y += __shfl_xor(acc.y, o);
            acc.z += __shfl_xor(acc.z, o);
            acc.w += __shfl_xor(acc.w, o);
        }
        if (lane < 16) {
            rred[wv][lane * 4 + 0] = acc.x;
            rred[wv][lane * 4 + 1] = acc.y;
            rred[wv][lane * 4 + 2] = acc.z;
            rred[wv][lane * 4 + 3] = acc.w;
        }
    }
    __syncthreads();
    if (t < Dd) {
        float r = 0.f;
        #pragma unroll
        for (int w = 0; w < NW; ++w) r += rred[w][t];
        out_r[(size_t)b * Dd + t] = r;
    }
}

extern "C" void kernel_launch(void* const* d_in, const int* in_sizes, int n_in,
                              void* d_out, int out_size, void* d_ws, size_t ws_size,
                              hipStream_t stream) {
    const float* co    = (const float*)d_in[0];   // (B, C)
    const float* wprev = (const float*)d_in[1];   // (B, N)
    const float* M     = (const float*)d_in[2];   // (B, N, D)
    const float* W     = (const float*)d_in[3];   // (C, 70)
    const float* bias  = (const float*)d_in[4];   // (70,)
    float* out = (float*)d_out;                   // r_t (B*D) then w_t (B*N)
    float* out_r = out;
    float* out_w = out + (size_t)Bb * Dd;

    ntm_read_head_kernel<<<Bb, BLOCK, 0, stream>>>(co, wprev, M, W, bias, out_r, out_w);
}